// Round 1
// baseline (120.934 us; speedup 1.0000x reference)
//
#include <hip/hip_runtime.h>

// Shapes (fixed by the reference): B=N=16, C=256, D=512, H=W=16 (HW=256)
#define B_  16
#define N_  16
#define C_  256
#define D_  512
#define HW_ 256

// ws layout (float offsets)
#define WS_COLSUM 0        // 256  : sum_d vw[d,c]
#define WS_SB     256      // 1    : sum vb
#define WS_TEMAX  257      // 1
#define WS_TEMIN  258      // 1
#define WS_S      512      // 4096 : s[b,hw]
#define WS_SMAX   4608     // 16
#define WS_SMIN   4624     // 16
#define WS_VFMEAN 4640     // 4096 : mean_hw vf[b,c]
#define WS_VPMEAN 8736     // 8192 : mean_hw vp[b,d]
#define WS_Z      16928    // 16   : softmax denom per b
#define WS_TOTAL  16944

// K1: colsum of vw (blocks 0..7, atomics), te min/max + sum(vb) (block 8)
__global__ void k1_prep(const float* __restrict__ vw, const float* __restrict__ vb,
                        const float* __restrict__ te, float* __restrict__ ws) {
  int tid = threadIdx.x, bid = blockIdx.x;
  if (bid < 8) {
    float acc = 0.f;
    int c = tid;
    int d0 = bid * 64;
    #pragma unroll 4
    for (int d = d0; d < d0 + 64; ++d) acc += vw[d * C_ + c];
    atomicAdd(&ws[WS_COLSUM + c], acc);
  } else {
    float mx = -1e30f, mn = 1e30f, sb = 0.f;
    for (int i = tid; i < N_ * D_; i += 256) {
      float v = te[i];
      mx = fmaxf(mx, v); mn = fminf(mn, v);
    }
    for (int i = tid; i < D_; i += 256) sb += vb[i];
    for (int m = 32; m; m >>= 1) {
      mx = fmaxf(mx, __shfl_xor(mx, m));
      mn = fminf(mn, __shfl_xor(mn, m));
      sb += __shfl_xor(sb, m);
    }
    __shared__ float smx[4], smn[4], ssb[4];
    int w = tid >> 6;
    if ((tid & 63) == 0) { smx[w] = mx; smn[w] = mn; ssb[w] = sb; }
    __syncthreads();
    if (tid == 0) {
      ws[WS_TEMAX] = fmaxf(fmaxf(smx[0], smx[1]), fmaxf(smx[2], smx[3]));
      ws[WS_TEMIN] = fminf(fminf(smn[0], smn[1]), fminf(smn[2], smn[3]));
      ws[WS_SB]    = ssb[0] + ssb[1] + ssb[2] + ssb[3];
    }
  }
}

// K3: vfmean[b,c] = mean over 256 spatial of vf. One wave per (b,c).
__global__ void k3_vfmean(const float* __restrict__ vf, float* __restrict__ ws) {
  int bid = blockIdx.x;          // b*C_ + c
  int tid = threadIdx.x;         // 64
  float4 v = ((const float4*)(vf + (size_t)bid * HW_))[tid];
  float s = v.x + v.y + v.z + v.w;
  for (int m = 32; m; m >>= 1) s += __shfl_xor(s, m);
  if (tid == 0) ws[WS_VFMEAN + bid] = s * (1.0f / HW_);
}

// K2: s[b,hw] = dot(vf[b,:,hw], colsum) + sb; also per-b min/max of s.
__global__ void k2_s(const float* __restrict__ vf, float* __restrict__ ws) {
  int b = blockIdx.x, tid = threadIdx.x;
  __shared__ float cw[C_];
  cw[tid] = ws[WS_COLSUM + tid];
  __syncthreads();
  const float* vfb = vf + (size_t)b * C_ * HW_;
  float acc = 0.f;
  #pragma unroll 4
  for (int c = 0; c < C_; ++c) acc += vfb[c * HW_ + tid] * cw[c];
  acc += ws[WS_SB];
  ws[WS_S + b * HW_ + tid] = acc;
  float mx = acc, mn = acc;
  for (int m = 32; m; m >>= 1) {
    mx = fmaxf(mx, __shfl_xor(mx, m));
    mn = fminf(mn, __shfl_xor(mn, m));
  }
  __shared__ float smx[4], smn[4];
  int w = tid >> 6;
  if ((tid & 63) == 0) { smx[w] = mx; smn[w] = mn; }
  __syncthreads();
  if (tid == 0) {
    ws[WS_SMAX + b] = fmaxf(fmaxf(smx[0], smx[1]), fmaxf(smx[2], smx[3]));
    ws[WS_SMIN + b] = fminf(fminf(smn[0], smn[1]), fminf(smn[2], smn[3]));
  }
}

// K4: vpmean[b,dd] = dot(vfmean[b,:], vw[dd,:]) + vb[dd]
__global__ void k4_vpmean(const float* __restrict__ vw, const float* __restrict__ vb,
                          float* __restrict__ ws) {
  int id = blockIdx.x * 256 + threadIdx.x;
  int b = id >> 9, dd = id & (D_ - 1);
  __shared__ float vfm[C_];
  vfm[threadIdx.x] = ws[WS_VFMEAN + b * C_ + threadIdx.x];
  __syncthreads();
  float acc = vb[dd];
  const float* row = vw + (size_t)dd * C_;
  #pragma unroll 4
  for (int c = 0; c < C_; ++c) acc += vfm[c] * row[c];
  ws[WS_VPMEAN + id] = acc;
}

// K5: final[b,d] = mtf[b,:].iw[d,0:512] + vpmean[b,:].iw[d,512:1024] + ib[d]
__global__ void k5_final(const float* __restrict__ mtf, const float* __restrict__ iw,
                         const float* __restrict__ ib, const float* __restrict__ ws,
                         float* __restrict__ out) {
  int id = blockIdx.x * 256 + threadIdx.x;
  int b = id >> 9, d = id & (D_ - 1);
  __shared__ float a[D_], p[D_];
  a[threadIdx.x]       = mtf[b * D_ + threadIdx.x];
  a[threadIdx.x + 256] = mtf[b * D_ + threadIdx.x + 256];
  p[threadIdx.x]       = ws[WS_VPMEAN + b * D_ + threadIdx.x];
  p[threadIdx.x + 256] = ws[WS_VPMEAN + b * D_ + threadIdx.x + 256];
  __syncthreads();
  float acc = ib[d];
  const float* row = iw + (size_t)d * (2 * D_);
  #pragma unroll 4
  for (int c = 0; c < D_; ++c)
    acc += a[c] * row[c] + p[c] * row[D_ + c];
  out[id] = acc;
}

__device__ inline float corner_max(const float* ws, int b) {
  float tmax = ws[WS_TEMAX], tmin = ws[WS_TEMIN];
  float smax = ws[WS_SMAX + b], smin = ws[WS_SMIN + b];
  return fmaxf(fmaxf(tmax * smax, tmax * smin), fmaxf(tmin * smax, tmin * smin));
}

// K6: Z[b] = sum_{n,d,h,w} exp(te[n,d]*s[b,hw] - m_b). 32 blocks per b.
__global__ void k6_z(const float* __restrict__ te, float* __restrict__ ws) {
  int bid = blockIdx.x;
  int b = bid >> 5, chunk = bid & 31;
  int tid = threadIdx.x;
  __shared__ float sl[HW_];
  sl[tid] = ws[WS_S + b * HW_ + tid];
  __syncthreads();
  float m = corner_max(ws, b);
  float t = te[chunk * 256 + tid];
  float acc = 0.f;
  #pragma unroll 4
  for (int hw = 0; hw < HW_; ++hw) acc += __expf(t * sl[hw] - m);
  for (int mm = 32; mm; mm >>= 1) acc += __shfl_xor(acc, mm);
  __shared__ float part[4];
  if ((tid & 63) == 0) part[tid >> 6] = acc;
  __syncthreads();
  if (tid == 0) atomicAdd(&ws[WS_Z + b], part[0] + part[1] + part[2] + part[3]);
}

// K7: attn[b,n,d,hw] = exp(te[n,d]*s[b,hw] - m_b) / Z[b]. 16 rows/block, float4 stores.
__global__ void k7_attn(const float* __restrict__ te, const float* __restrict__ ws,
                        float* __restrict__ out) {
  int bid = blockIdx.x, tid = threadIdx.x;
  int r0 = bid * 16;                 // global row = b*8192 + nd, 16 rows per block
  int b = r0 >> 13;
  __shared__ float sl[HW_];
  sl[tid] = ws[WS_S + b * HW_ + tid];
  __syncthreads();
  float m = corner_max(ws, b);
  float invZ = 1.0f / ws[WS_Z + b];
  int lane = tid & 63;
  float4 sv = ((const float4*)sl)[lane];
  float* attn = out + N_ * D_;       // skip final (8192 floats)
  #pragma unroll
  for (int i = 0; i < 4; ++i) {
    int row = r0 + (tid >> 6) + i * 4;
    float t = te[row & (N_ * D_ - 1)];
    float4 o;
    o.x = __expf(t * sv.x - m) * invZ;
    o.y = __expf(t * sv.y - m) * invZ;
    o.z = __expf(t * sv.z - m) * invZ;
    o.w = __expf(t * sv.w - m) * invZ;
    ((float4*)(attn + (size_t)row * HW_))[lane] = o;
  }
}

extern "C" void kernel_launch(void* const* d_in, const int* in_sizes, int n_in,
                              void* d_out, int out_size, void* d_ws, size_t ws_size,
                              hipStream_t stream) {
  const float* mtf = (const float*)d_in[0];  // masked_text_features [16,512]
  const float* vf  = (const float*)d_in[1];  // visual_features [16,256,16,16]
  const float* te  = (const float*)d_in[2];  // text_embeddings [16,512]
  const float* vw  = (const float*)d_in[3];  // visual_proj_w [512,256]
  const float* vb  = (const float*)d_in[4];  // visual_proj_b [512]
  const float* iw  = (const float*)d_in[5];  // interaction_w [512,1024]
  const float* ib  = (const float*)d_in[6];  // interaction_b [512]
  float* out = (float*)d_out;
  float* ws  = (float*)d_ws;

  hipMemsetAsync(ws, 0, WS_TOTAL * sizeof(float), stream);
  k1_prep  <<<9,        256, 0, stream>>>(vw, vb, te, ws);
  k3_vfmean<<<B_ * C_,  64,  0, stream>>>(vf, ws);
  k2_s     <<<B_,       256, 0, stream>>>(vf, ws);
  k4_vpmean<<<32,       256, 0, stream>>>(vw, vb, ws);
  k5_final <<<32,       256, 0, stream>>>(mtf, iw, ib, ws, out);
  k6_z     <<<512,      256, 0, stream>>>(te, ws);
  k7_attn  <<<N_ * D_ * B_ / 16, 256, 0, stream>>>(te, ws, out);
}

// Round 2
// 106.541 us; speedup vs baseline: 1.1351x; 1.1351x over previous
//
#include <hip/hip_runtime.h>

// Shapes (fixed by the reference): B=N=16, C=256, D=512, H=W=16 (HW=256)
#define B_  16
#define N_  16
#define C_  256
#define D_  512
#define HW_ 256

// ws layout (float offsets) — every slot is WRITTEN every call (no atomics,
// no memset needed; deterministic under graph replay).
#define WS_COLSUM 0        // 256  : sum_d vw[d,c]
#define WS_SB     256      // 1    : sum vb
#define WS_TEMAX  257      // 1
#define WS_TEMIN  258      // 1
#define WS_S      512      // 4096 : s[b,hw]
#define WS_SMAX   4608     // 16
#define WS_SMIN   4624     // 16
#define WS_VFMEAN 4640     // 4096 : mean_hw vf[b,c]
#define WS_VPMEAN 8736     // 8192 : vpmean[b,d]
#define WS_ZP     16928    // 512  : Z partials, 32 per b

__device__ inline float corner_max(const float* ws, float smax, float smin) {
  float tmax = ws[WS_TEMAX], tmin = ws[WS_TEMIN];
  return fmaxf(fmaxf(tmax * smax, tmax * smin), fmaxf(tmin * smax, tmin * smin));
}

// ---------------- Kernel A: prep ----------------
// block 0: colsum of vw; block 1: te min/max + sum(vb); blocks 2..1025: vfmean
__global__ void kA(const float* __restrict__ vw, const float* __restrict__ vb,
                   const float* __restrict__ te, const float* __restrict__ vf,
                   float* __restrict__ ws) {
  int bid = blockIdx.x, tid = threadIdx.x;
  if (bid == 0) {
    float acc = 0.f;
    #pragma unroll 8
    for (int d = 0; d < D_; ++d) acc += vw[d * C_ + tid];
    ws[WS_COLSUM + tid] = acc;
  } else if (bid == 1) {
    float mx = -1e30f, mn = 1e30f, sb = 0.f;
    for (int i = tid; i < N_ * D_; i += 256) {
      float v = te[i];
      mx = fmaxf(mx, v); mn = fminf(mn, v);
    }
    for (int i = tid; i < D_; i += 256) sb += vb[i];
    for (int m = 32; m; m >>= 1) {
      mx = fmaxf(mx, __shfl_xor(mx, m));
      mn = fminf(mn, __shfl_xor(mn, m));
      sb += __shfl_xor(sb, m);
    }
    __shared__ float smx[4], smn[4], ssb[4];
    int w = tid >> 6;
    if ((tid & 63) == 0) { smx[w] = mx; smn[w] = mn; ssb[w] = sb; }
    __syncthreads();
    if (tid == 0) {
      ws[WS_TEMAX] = fmaxf(fmaxf(smx[0], smx[1]), fmaxf(smx[2], smx[3]));
      ws[WS_TEMIN] = fminf(fminf(smn[0], smn[1]), fminf(smn[2], smn[3]));
      ws[WS_SB]    = ssb[0] + ssb[1] + ssb[2] + ssb[3];
    }
  } else {
    // vfmean: one wave per (b,c) row, 4 rows per block
    int row  = (bid - 2) * 4 + (tid >> 6);   // b*C_ + c
    int lane = tid & 63;
    float4 v = ((const float4*)(vf + (size_t)row * HW_))[lane];
    float s = v.x + v.y + v.z + v.w;
    for (int m = 32; m; m >>= 1) s += __shfl_xor(s, m);
    if (lane == 0) ws[WS_VFMEAN + row] = s * (1.0f / HW_);
  }
}

// ---------------- Kernel B: s, vpmean, Z-partials ----------------
// blocks 0..15: s[b,:] + per-b min/max
// blocks 16..47: vpmean
// blocks 48..559: Z partial for (b,chunk); recomputes s[b,:] locally
__global__ void kB(const float* __restrict__ vf, const float* __restrict__ vw,
                   const float* __restrict__ vb, const float* __restrict__ te,
                   float* __restrict__ ws) {
  int bid = blockIdx.x, tid = threadIdx.x;
  if (bid < 16) {
    int b = bid;
    __shared__ float cw[C_];
    cw[tid] = ws[WS_COLSUM + tid];
    __syncthreads();
    const float* vfb = vf + (size_t)b * C_ * HW_;
    float acc = ws[WS_SB];
    #pragma unroll 4
    for (int c = 0; c < C_; ++c) acc += vfb[c * HW_ + tid] * cw[c];
    ws[WS_S + b * HW_ + tid] = acc;
    float mx = acc, mn = acc;
    for (int m = 32; m; m >>= 1) {
      mx = fmaxf(mx, __shfl_xor(mx, m));
      mn = fminf(mn, __shfl_xor(mn, m));
    }
    __shared__ float smx[4], smn[4];
    int w = tid >> 6;
    if ((tid & 63) == 0) { smx[w] = mx; smn[w] = mn; }
    __syncthreads();
    if (tid == 0) {
      ws[WS_SMAX + b] = fmaxf(fmaxf(smx[0], smx[1]), fmaxf(smx[2], smx[3]));
      ws[WS_SMIN + b] = fminf(fminf(smn[0], smn[1]), fminf(smn[2], smn[3]));
    }
  } else if (bid < 48) {
    // vpmean[b,dd] = dot(vfmean[b,:], vw[dd,:]) + vb[dd]
    int id = (bid - 16) * 256 + tid;
    int b = id >> 9, dd = id & (D_ - 1);
    __shared__ float vfm[C_];
    vfm[tid] = ws[WS_VFMEAN + b * C_ + tid];
    __syncthreads();
    float acc = vb[dd];
    const float* row = vw + (size_t)dd * C_;
    #pragma unroll 4
    for (int c = 0; c < C_; ++c) acc += vfm[c] * row[c];
    ws[WS_VPMEAN + id] = acc;
  } else {
    // Z partial: z = (b,chunk). Recompute s[b,:] locally, then 256x256 exps.
    int z = bid - 48, b = z >> 5, chunk = z & 31;
    __shared__ float cw[C_];
    __shared__ float sl[HW_];
    cw[tid] = ws[WS_COLSUM + tid];
    __syncthreads();
    const float* vfb = vf + (size_t)b * C_ * HW_;
    float acc = ws[WS_SB];
    #pragma unroll 4
    for (int c = 0; c < C_; ++c) acc += vfb[c * HW_ + tid] * cw[c];
    sl[tid] = acc;
    float mx = acc, mn = acc;
    for (int m = 32; m; m >>= 1) {
      mx = fmaxf(mx, __shfl_xor(mx, m));
      mn = fminf(mn, __shfl_xor(mn, m));
    }
    __shared__ float smx[4], smn[4];
    int w = tid >> 6;
    if ((tid & 63) == 0) { smx[w] = mx; smn[w] = mn; }
    __syncthreads();
    float bmx = fmaxf(fmaxf(smx[0], smx[1]), fmaxf(smx[2], smx[3]));
    float bmn = fminf(fminf(smn[0], smn[1]), fminf(smn[2], smn[3]));
    float m = corner_max(ws, bmx, bmn);
    float t = te[chunk * 256 + tid];
    float zacc = 0.f;
    #pragma unroll 4
    for (int hw = 0; hw < HW_; ++hw) zacc += __expf(t * sl[hw] - m);
    for (int mm = 32; mm; mm >>= 1) zacc += __shfl_xor(zacc, mm);
    __shared__ float part[4];
    if ((tid & 63) == 0) part[tid >> 6] = zacc;
    __syncthreads();
    if (tid == 0) ws[WS_ZP + z] = part[0] + part[1] + part[2] + part[3];
  }
}

// ---------------- Kernel D: attn + final ----------------
// blocks 0..8191: attn (16 rows each); blocks 8192..8223: final
__global__ void kD(const float* __restrict__ te, const float* __restrict__ mtf,
                   const float* __restrict__ iw, const float* __restrict__ ib,
                   const float* __restrict__ ws, float* __restrict__ out) {
  int bid = blockIdx.x, tid = threadIdx.x;
  if (bid >= 8192) {
    // final[b,d] = mtf[b,:].iw[d,0:512] + vpmean[b,:].iw[d,512:1024] + ib[d]
    int id = (bid - 8192) * 256 + tid;
    int b = id >> 9, d = id & (D_ - 1);
    __shared__ float a[D_], p[D_];
    int half = (id >> 8) & 1;   // which half of this b's 512 this block covers
    (void)half;
    a[tid]       = mtf[b * D_ + tid];
    a[tid + 256] = mtf[b * D_ + tid + 256];
    p[tid]       = ws[WS_VPMEAN + b * D_ + tid];
    p[tid + 256] = ws[WS_VPMEAN + b * D_ + tid + 256];
    __syncthreads();
    float acc = ib[d];
    const float* row = iw + (size_t)d * (2 * D_);
    #pragma unroll 4
    for (int c = 0; c < D_; ++c)
      acc += a[c] * row[c] + p[c] * row[D_ + c];
    out[id] = acc;
    return;
  }
  // attn
  int r0 = bid * 16;                 // global row = b*8192 + nd
  int b = r0 >> 13;
  __shared__ float sl[HW_];
  __shared__ float sinvZ;
  sl[tid] = ws[WS_S + b * HW_ + tid];
  if (tid < 32) {
    float pz = ws[WS_ZP + b * 32 + tid];
    for (int m = 16; m; m >>= 1) pz += __shfl_xor(pz, m);
    if (tid == 0) sinvZ = 1.0f / pz;
  }
  __syncthreads();
  float m = corner_max(ws, ws[WS_SMAX + b], ws[WS_SMIN + b]);
  float invZ = sinvZ;
  int lane = tid & 63;
  float4 sv = ((const float4*)sl)[lane];
  float* attn = out + N_ * D_;       // skip final (8192 floats)
  #pragma unroll
  for (int i = 0; i < 4; ++i) {
    int row = r0 + (tid >> 6) + i * 4;
    float t = te[row & (N_ * D_ - 1)];
    float4 o;
    o.x = __expf(t * sv.x - m) * invZ;
    o.y = __expf(t * sv.y - m) * invZ;
    o.z = __expf(t * sv.z - m) * invZ;
    o.w = __expf(t * sv.w - m) * invZ;
    ((float4*)(attn + (size_t)row * HW_))[lane] = o;
  }
}

extern "C" void kernel_launch(void* const* d_in, const int* in_sizes, int n_in,
                              void* d_out, int out_size, void* d_ws, size_t ws_size,
                              hipStream_t stream) {
  const float* mtf = (const float*)d_in[0];  // masked_text_features [16,512]
  const float* vf  = (const float*)d_in[1];  // visual_features [16,256,16,16]
  const float* te  = (const float*)d_in[2];  // text_embeddings [16,512]
  const float* vw  = (const float*)d_in[3];  // visual_proj_w [512,256]
  const float* vb  = (const float*)d_in[4];  // visual_proj_b [512]
  const float* iw  = (const float*)d_in[5];  // interaction_w [512,1024]
  const float* ib  = (const float*)d_in[6];  // interaction_b [512]
  float* out = (float*)d_out;
  float* ws  = (float*)d_ws;

  kA<<<1026, 256, 0, stream>>>(vw, vb, te, vf, ws);
  kB<<<560,  256, 0, stream>>>(vf, vw, vb, te, ws);
  kD<<<8224, 256, 0, stream>>>(te, mtf, iw, ib, ws, out);
}